// Round 1
// 192.043 us; speedup vs baseline: 1.0126x; 1.0126x over previous
//
#include <hip/hip_runtime.h>

// EOQLinear: int4-quantized GEMV.
//   out[n] = sum_b scales[n,b] * sum_{q in block b} w_int[n,q] * x[q]
// packed_w[n,j] is an int32 in [0,256): low nibble -> k=2j, high nibble -> k=2j+1, -8.
//
// DTYPE NOTE (round-1): harness stages the reference's float16 tensors as FLOAT32.
//
// ROUND-13. Evidence recap: five structures all pin the kernel at ~54-60 us
// (2.35-2.4 TB/s demand read) while the identical code reads 6.2 TB/s when
// L3-resident and the harness fills write at 6.8 TB/s. Concurrency math says
// >=4 MiB of loads are in flight device-wide -> not latency/occupancy bound.
// Surviving mechanism: demand reads ALLOCATE into L2/MALL and the
// allocation/victim path throttles at ~2.4 TB/s. Round-12 tested
// __builtin_nontemporal_load -> NO CHANGE, but that builtin emits only the
// `nt` retention hint. The SCOPE bits (sc0 sc1, the gfx940+ replacement for
// glc/slc) are what move the service/allocation point up the hierarchy, and
// they are only reachable via inline asm. This round: round-6 known-good
// structure + weight loads as `global_load_dwordx4 ... sc0 sc1 nt`
// (maximal bypass/stream encoding). ONE variable changed.
//
// Hazard control (guide ERRATA #18): asm loads are async; the drain
// `s_waitcnt vmcnt(0)` takes the four result quads as "+v" operands so the
// consume phase has a true data dependence on the wait, plus sched_barrier(0).
// Compiler-inserted waits for its own (cached) x/scale loads stay safe:
// vmcnt retires in order, so unknown extra outstanding ops only strengthen
// its waits.
//
// Layout: one 64-lane wave per output row, 4 rows per 256-thread block
// (2048 blocks, zero LDS). Weights: 16 B asm loads, 1 KiB contiguous per
// wave-instruction, 4 issued per unroll block then drained. x: 32 KB
// cache-resident, 2x float4 per chunk (normal cached loads). Scale: one per
// 4-int chunk (srow[j >> sShift]); fp32 acc, butterfly reduce.

typedef int   iv4 __attribute__((ext_vector_type(4)));

#define WAVES_PER_BLOCK 4

__device__ __forceinline__ float dot8(iv4 w, float4 xa, float4 xb)
{
    const unsigned w0 = (unsigned)w.x;
    const unsigned w1 = (unsigned)w.y;
    const unsigned w2 = (unsigned)w.z;
    const unsigned w3 = (unsigned)w.w;
    float part = 0.f;
    part = fmaf((float)(int)(w0 & 0xFu) - 8.f, xa.x, part);
    part = fmaf((float)(int)(w0 >> 4)   - 8.f, xa.y, part);
    part = fmaf((float)(int)(w1 & 0xFu) - 8.f, xa.z, part);
    part = fmaf((float)(int)(w1 >> 4)   - 8.f, xa.w, part);
    part = fmaf((float)(int)(w2 & 0xFu) - 8.f, xb.x, part);
    part = fmaf((float)(int)(w2 >> 4)   - 8.f, xb.y, part);
    part = fmaf((float)(int)(w3 & 0xFu) - 8.f, xb.z, part);
    part = fmaf((float)(int)(w3 >> 4)   - 8.f, xb.w, part);
    return part;
}

__global__ __launch_bounds__(256, 4)
void eoq_gemv_kernel(const float* __restrict__ x,
                     const int* __restrict__ packed_w,
                     const float* __restrict__ scales,
                     float* __restrict__ out,
                     int N, int halfK, int iters, int sShift, int blocksPerRow)
{
    const int lane = threadIdx.x & 63;
    const int wave = threadIdx.x >> 6;
    const int row  = blockIdx.x * WAVES_PER_BLOCK + wave;
    if (row >= N) return;

    const iv4*    __restrict__ w4p =
        reinterpret_cast<const iv4*>(packed_w + (size_t)row * halfK);
    const float4* __restrict__ x4p = reinterpret_cast<const float4*>(x);
    const float*  __restrict__ srow = scales + (size_t)row * blocksPerRow;

    float acc = 0.f;

    // iters = halfK/256 = 16 for K=8192; always a multiple of 4 here.
    for (int it = 0; it < iters; it += 4) {
        const int j0 = ((it + 0) << 6) + lane;   // 16B-chunk indices in the row
        const int j1 = ((it + 1) << 6) + lane;
        const int j2 = ((it + 2) << 6) + lane;
        const int j3 = ((it + 3) << 6) + lane;

        // ---- issue phase: 4 streaming weight loads, no cache allocation ----
        iv4 w0, w1, w2, w3;
        asm volatile("global_load_dwordx4 %0, %1, off sc0 sc1 nt"
                     : "=v"(w0) : "v"(w4p + j0));
        asm volatile("global_load_dwordx4 %0, %1, off sc0 sc1 nt"
                     : "=v"(w1) : "v"(w4p + j1));
        asm volatile("global_load_dwordx4 %0, %1, off sc0 sc1 nt"
                     : "=v"(w2) : "v"(w4p + j2));
        asm volatile("global_load_dwordx4 %0, %1, off sc0 sc1 nt"
                     : "=v"(w3) : "v"(w4p + j3));

        // x and scales: normal cached loads (32 KB x stays L1/L2-resident).
        const float4 xa0 = x4p[2 * j0], xb0 = x4p[2 * j0 + 1];
        const float4 xa1 = x4p[2 * j1], xb1 = x4p[2 * j1 + 1];
        const float4 xa2 = x4p[2 * j2], xb2 = x4p[2 * j2 + 1];
        const float4 xa3 = x4p[2 * j3], xb3 = x4p[2 * j3 + 1];
        const float  s0 = srow[j0 >> sShift];
        const float  s1 = srow[j1 >> sShift];
        const float  s2 = srow[j2 >> sShift];
        const float  s3 = srow[j3 >> sShift];

        // ---- drain: consumers below data-depend on this asm's outputs ----
        asm volatile("s_waitcnt vmcnt(0)"
                     : "+v"(w0), "+v"(w1), "+v"(w2), "+v"(w3)
                     :
                     : "memory");
        __builtin_amdgcn_sched_barrier(0);

        // ---- consume phase ----
        acc = fmaf(s0, dot8(w0, xa0, xb0), acc);
        acc = fmaf(s1, dot8(w1, xa1, xb1), acc);
        acc = fmaf(s2, dot8(w2, xa2, xb2), acc);
        acc = fmaf(s3, dot8(w3, xa3, xb3), acc);
    }

    // wave-64 butterfly reduction
    #pragma unroll
    for (int off = 32; off > 0; off >>= 1)
        acc += __shfl_down(acc, off, 64);

    if (lane == 0) out[row] = acc;
}

extern "C" void kernel_launch(void* const* d_in, const int* in_sizes, int n_in,
                              void* d_out, int out_size, void* d_ws, size_t ws_size,
                              hipStream_t stream) {
    const float* x      = (const float*)d_in[0];
    const int*   pw     = (const int*)d_in[1];
    const float* scales = (const float*)d_in[2];
    float*       out    = (float*)d_out;

    const int K     = in_sizes[0];         // 8192
    const int halfK = K >> 1;              // 4096
    const int N     = in_sizes[1] / halfK; // 8192
    const int blocksPerRow = in_sizes[2] / N;    // K/QB = 64

    // packed ints per quant block = QB/2 = halfK/blocksPerRow (pow2);
    // sShift: 16B-chunk index -> quant-block index = log2(QB/2) - 2 (QB=128 -> 4)
    const int qhalf = halfK / blocksPerRow;
    int qhalfShift = 0;
    while ((1 << qhalfShift) < qhalf) ++qhalfShift;
    const int sShift = qhalfShift - 2;

    const int iters = halfK >> 8;          // 16B-chunk steps per row (16)

    dim3 grid((N + WAVES_PER_BLOCK - 1) / WAVES_PER_BLOCK), block(256);
    eoq_gemv_kernel<<<grid, block, 0, stream>>>(x, pw, scales, out,
                                                N, halfK, iters, sShift, blocksPerRow);
}